// Round 20
// baseline (79.590 us; speedup 1.0000x reference)
//
#include <hip/hip_runtime.h>
#include <hip/hip_bf16.h>
#include <stdint.h>

// Problem constants
#define B_  64
#define C_  3
#define H_  512
#define W_  512
#define OC_ 16
#define OH_ 510
#define OW_ 510

// SINGLE-KERNEL version of R19 (prep folded in: no second launch, no d_ws).
// Block = 128 threads = 2 INDEPENDENT waves (no __syncthreads anywhere).
// Each wave: 64-px x 16-row strip = 4 subtiles of 4 rows, software-pipelined
// through a 3ch x 6-row LDS ring (slot = row mod 6). Per subtile: 4 groups
// (2 rows x 32 px), 3 MFMA 32x32x16. M=32 rows carry (v,oc) PERMUTED so that
// C-layout row=(reg&3)+8*(reg>>2)+4*hi gives: hi half-wave == v, regs == all
// 16 oc -> channel-min is PURE IN-LANE (no bpermute).
//   row r: v = (r>>2)&1, oc = (r&3) | ((r>>3)<<2)
#define TILES_X_ 8     // ox0 = min(64bx, 446) overlap tile
#define YBLK_    16    // 2 waves/block -> 32 strips of 16 rows (oyw<=494)
#define PXW_     68    // u32 pair slots per line (x=0..67; reads reach x=65)
#define LPW_     (C_ * 6 * PXW_)   // 18 lines * 68 = wave-private ring

typedef __attribute__((ext_vector_type(8)))  short bf16x8;   // MFMA A/B frag
typedef __attribute__((ext_vector_type(16))) float f32x16;   // MFMA C/D frag

// NaN-safe tanh: 1 - 2/(e^{2x}+1); e=inf -> 1 (no inf/inf NaN).
__device__ __forceinline__ float fast_tanh(float v) {
    float e = __expf(2.0f * v);
    return 1.0f - 2.0f * __builtin_amdgcn_rcpf(e + 1.0f);
}
__device__ __forceinline__ uint16_t bf16u(float f) {
    __hip_bfloat16 h = __float2bfloat16(f);   // RNE
    return __builtin_bit_cast(uint16_t, h);
}
__device__ __forceinline__ uint32_t pack2bf(float v0, float v1) {
    return (uint32_t)bf16u(v0) | ((uint32_t)bf16u(v1) << 16);
}
__device__ __forceinline__ float4 ld_f4(const float* p) {
    float4 v;
    __builtin_memcpy(&v, p, 16);   // global_load_dwordx4
    return v;
}

__global__ __launch_bounds__(128)
void conv3x3_min_tanh_mfma(const float* __restrict__ x,
                           const float* __restrict__ wgt,
                           const float* __restrict__ bias,
                           float* __restrict__ out) {
    __shared__ uint32_t lds[2 * LPW_];   // 2 x 4896 B

    const int blk = blockIdx.x;
    const int bx = blk % TILES_X_;
    const int by = (blk / TILES_X_) % YBLK_;
    const int b  = blk / (TILES_X_ * YBLK_);
    const int ox0 = min(bx * 64, OW_ - 64);   // <= 446

    const int tid  = threadIdx.x;
    const int lane = tid & 63;
    const int wv   = tid >> 6;           // 0..1 (independent waves)
    const int pcol = lane & 31;
    const int hi   = lane >> 5;

    const int sy  = 2 * by + wv;                 // 0..31
    const int oyw = min(16 * sy, OH_ - 16);      // <= 494; window rows <= 511

    const float* xb = x + (size_t)b * (C_ * H_ * W_);
    uint32_t* px = lds + wv * LPW_;              // wave-private ring

    // ---- prologue: window rows 0..5 -> slots 0..5 (18 lines) ----
    #pragma unroll
    for (int pass = 0; pass < 5; ++pass) {
        int i = pass * 64 + lane;
        if (pass < 4 || lane < 32) {     // 288 items
            int line = i >> 4;           // c*6 + r
            int x0   = 4 * (i & 15);
            int c    = (line >= 6) + (line >= 12);
            int r    = line - 6 * c;
            const float* xrow = xb + ((size_t)(c * H_) + (oyw + r)) * W_ + ox0;
            float4 v = ld_f4(xrow + x0);
            float v4 = xrow[x0 + 4];
            uint4 pk;
            pk.x = pack2bf(v.x, v.y);
            pk.y = pack2bf(v.y, v.z);
            pk.z = pack2bf(v.z, v.w);
            pk.w = pack2bf(v.w, v4);
            *reinterpret_cast<uint4*>(&px[line * PXW_ + x0]) = pk;
        }
    }
    if (lane < 36) {                     // extras x=64,65 per line
        int line = lane >> 1;
        int xx   = 64 + (lane & 1);
        int c    = (line >= 6) + (line >= 12);
        int r    = line - 6 * c;
        const float* xrow = xb + ((size_t)(c * H_) + (oyw + r)) * W_;
        float v0 = xrow[ox0 + xx];
        float v1 = xrow[min(ox0 + xx + 1, W_ - 1)];
        px[line * PXW_ + xx] = pack2bf(v0, v1);
    }

    // ---- INLINE prep (was separate kernel): per-lane A-frags + bias C-init.
    // wgt (1.7 KB) / bias (64 B) are L1/L2-hot; math hides under the staging
    // loads above. A[m][k]: m -> v=(m>>2)&1, oc=(m&3)|((m>>3)<<2);
    // k: p=k>>1, h=k&1; wr=p>>1, pk=p&1; kx = pk ? (h? INVALID : 2) : h;
    // ky = wr - v; w = wgt[oc][c][ky][kx] or 0.
    const int mrv = (pcol >> 2) & 1;                    // v of this lane's M-row
    const int moc = (pcol & 3) | ((pcol >> 3) << 2);    // oc of this lane's M-row
    bf16x8 wfA0, wfA1, wfA2;
    #pragma unroll
    for (int e = 0; e < 8; ++e) {
        int k  = 8 * hi + e, p = k >> 1, h = k & 1;
        int wr = p >> 1, pk = p & 1;
        int kx = pk ? (h ? -1 : 2) : h;
        int ky = wr - mrv;
        bool ok = (kx >= 0) && (ky >= 0) && (ky <= 2);
        int base = moc * 27 + ky * 3 + kx;
        wfA0[e] = (short)bf16u(ok ? wgt[base] : 0.0f);
        wfA1[e] = (short)bf16u(ok ? wgt[base + 9] : 0.0f);
        wfA2[e] = (short)bf16u(ok ? wgt[base + 18] : 0.0f);
    }
    f32x16 biasv;
    #pragma unroll
    for (int reg = 0; reg < 16; ++reg) {
        int row = (reg & 3) + 8 * (reg >> 2) + 4 * hi;
        biasv[reg] = bias[(row & 3) | ((row >> 3) << 2)];
    }

    const size_t obase0 = ((size_t)b * OH_ + oyw) * OW_ + ox0 + pcol;

    asm volatile("s_waitcnt lgkmcnt(0)" ::: "memory");
    __builtin_amdgcn_sched_barrier(0);

    // ---- per subtile t: groups gi (row-pair), xh (x-half); ring slots
    //      s = (4t + 2gi + 2hi (+1)) mod 6 -- compile-time per hi branch.
    //      Epilogue: PURE IN-LANE 15-fmin (A-row permutation), no bpermute. ----
#define GROUP(t, gi, xh)                                                       \
    {                                                                          \
        const int j  = pcol + 32 * (xh);                                       \
        const int s0 = hi ? ((4*(t) + 2*(gi) + 2) % 6) : ((4*(t) + 2*(gi)) % 6);     \
        const int s1 = hi ? ((4*(t) + 2*(gi) + 3) % 6) : ((4*(t) + 2*(gi) + 1) % 6); \
        const int b00 = (0 * 6 + s0) * PXW_ + j, b01 = (0 * 6 + s1) * PXW_ + j;\
        const int b10 = (1 * 6 + s0) * PXW_ + j, b11 = (1 * 6 + s1) * PXW_ + j;\
        const int b20 = (2 * 6 + s0) * PXW_ + j, b21 = (2 * 6 + s1) * PXW_ + j;\
        bf16x8 tb0 = __builtin_bit_cast(bf16x8,                                \
            uint4{px[b00], px[b00 + 2], px[b01], px[b01 + 2]});                \
        bf16x8 tb1 = __builtin_bit_cast(bf16x8,                                \
            uint4{px[b10], px[b10 + 2], px[b11], px[b11 + 2]});                \
        bf16x8 tb2 = __builtin_bit_cast(bf16x8,                                \
            uint4{px[b20], px[b20 + 2], px[b21], px[b21 + 2]});                \
        f32x16 acc = __builtin_amdgcn_mfma_f32_32x32x16_bf16(wfA0, tb0, biasv, 0, 0, 0); \
        acc = __builtin_amdgcn_mfma_f32_32x32x16_bf16(wfA1, tb1, acc, 0, 0, 0);\
        acc = __builtin_amdgcn_mfma_f32_32x32x16_bf16(wfA2, tb2, acc, 0, 0, 0);\
        float n0 = fminf(acc[0], acc[1]),   n1 = fminf(acc[2], acc[3]);        \
        float n2 = fminf(acc[4], acc[5]),   n3 = fminf(acc[6], acc[7]);        \
        float n4 = fminf(acc[8], acc[9]),   n5 = fminf(acc[10], acc[11]);      \
        float n6 = fminf(acc[12], acc[13]), n7 = fminf(acc[14], acc[15]);      \
        float mm = fminf(fminf(fminf(n0, n1), fminf(n2, n3)),                  \
                         fminf(fminf(n4, n5), fminf(n6, n7)));                 \
        float t_ = fast_tanh(fast_tanh(mm));                                   \
        out[obase0 + (size_t)(4 * (t) + 2 * (gi) + hi) * OW_ + 32 * (xh)] = t_;\
    }

    // pipelined iteration: issue loads (rows 4t+6..4t+9) -> compute subtile t
    // -> pack+write retired ring slots -> lgkm fence.
#define PIPE_ITER(t)                                                           \
    {                                                                          \
        const int rr_ = lane >> 4, ch_ = lane & 15;                            \
        const int gy_ = oyw + 4 * (t) + 6 + rr_;     /* <= 511 */              \
        const int xo_ = ox0 + 4 * ch_;                                         \
        const float* r0_ = xb + ((size_t)gy_) * W_ + xo_;                      \
        const float* r1_ = xb + ((size_t)(H_ + gy_)) * W_ + xo_;               \
        const float* r2_ = xb + ((size_t)(2 * H_ + gy_)) * W_ + xo_;           \
        float4 L0 = ld_f4(r0_); float E0 = r0_[4];                             \
        float4 L1 = ld_f4(r1_); float E1 = r1_[4];                             \
        float4 L2 = ld_f4(r2_); float E2 = r2_[4];                             \
        float X0 = 0.f, X1 = 0.f;                                              \
        if (lane < 24) {                                                       \
            int le_ = lane >> 1, ce_ = le_ >> 2, re_ = le_ & 3;                \
            int xx_ = 64 + (lane & 1);                                         \
            const float* xr_ = xb + ((size_t)(ce_ * H_) + (oyw + 4*(t) + 6 + re_)) * W_; \
            X0 = xr_[ox0 + xx_];                                               \
            X1 = xr_[min(ox0 + xx_ + 1, W_ - 1)];                              \
        }                                                                      \
        GROUP(t, 0, 0) GROUP(t, 0, 1) GROUP(t, 1, 0) GROUP(t, 1, 1)            \
        {                                                                      \
            const int sb_ = (4 * (t) + 6) % 6;       /* compile-time */        \
            int s_ = sb_ + rr_; s_ = (s_ >= 6) ? s_ - 6 : s_;                  \
            uint4 pk;                                                          \
            pk.x = pack2bf(L0.x, L0.y); pk.y = pack2bf(L0.y, L0.z);            \
            pk.z = pack2bf(L0.z, L0.w); pk.w = pack2bf(L0.w, E0);              \
            *reinterpret_cast<uint4*>(&px[(0 * 6 + s_) * PXW_ + 4 * ch_]) = pk;\
            pk.x = pack2bf(L1.x, L1.y); pk.y = pack2bf(L1.y, L1.z);            \
            pk.z = pack2bf(L1.z, L1.w); pk.w = pack2bf(L1.w, E1);              \
            *reinterpret_cast<uint4*>(&px[(1 * 6 + s_) * PXW_ + 4 * ch_]) = pk;\
            pk.x = pack2bf(L2.x, L2.y); pk.y = pack2bf(L2.y, L2.z);            \
            pk.z = pack2bf(L2.z, L2.w); pk.w = pack2bf(L2.w, E2);              \
            *reinterpret_cast<uint4*>(&px[(2 * 6 + s_) * PXW_ + 4 * ch_]) = pk;\
            if (lane < 24) {                                                   \
                int le_ = lane >> 1, ce_ = le_ >> 2, re_ = le_ & 3;            \
                int xx_ = 64 + (lane & 1);                                     \
                int se_ = sb_ + re_; se_ = (se_ >= 6) ? se_ - 6 : se_;         \
                px[(ce_ * 6 + se_) * PXW_ + xx_] = pack2bf(X0, X1);            \
            }                                                                  \
        }                                                                      \
        asm volatile("s_waitcnt lgkmcnt(0)" ::: "memory");                     \
        __builtin_amdgcn_sched_barrier(0);                                     \
    }

    PIPE_ITER(0)
    PIPE_ITER(1)
    PIPE_ITER(2)
    GROUP(3, 0, 0) GROUP(3, 0, 1) GROUP(3, 1, 0) GROUP(3, 1, 1)
#undef PIPE_ITER
#undef GROUP
}

extern "C" void kernel_launch(void* const* d_in, const int* in_sizes, int n_in,
                              void* d_out, int out_size, void* d_ws, size_t ws_size,
                              hipStream_t stream) {
    const float* x    = (const float*)d_in[0];
    const float* wgt  = (const float*)d_in[1];
    const float* bias = (const float*)d_in[2];
    float* out = (float*)d_out;

    conv3x3_min_tanh_mfma<<<dim3(B_ * TILES_X_ * YBLK_), 128, 0, stream>>>(
        x, wgt, bias, out);
}

// Round 21
// 73.046 us; speedup vs baseline: 1.0896x; 1.0896x over previous
//
#include <hip/hip_runtime.h>
#include <hip/hip_bf16.h>
#include <stdint.h>

// Problem constants
#define B_  64
#define C_  3
#define H_  512
#define W_  512
#define OC_ 16
#define OH_ 510
#define OW_ 510

// ROLLED + PERSISTENT version of R19. Same verified math:
//  - 32x32x16 MFMA, M=32 rows = (v,oc) permuted: v=(r>>2)&1, oc=(r&3)|((r>>3)<<2)
//    -> C-layout row=(reg&3)+8*(reg>>2)+4*hi gives pure in-lane channel-min.
//  - wave-private 3ch x 6-row LDS ring (slot = row mod 6), 64px x 16row strip.
// New: all loops rolled (hot code ~2.5 KB), grid = 4096 blocks (16/CU fully
// co-resident, 2 strips per wave), NO asm fences (per-wave DS is in-order;
// compiler orders aliasing LDS ops and inserts lgkmcnt for reg deps).
#define TILES_X_ 8
#define SYMAX_   32                       // y-strips per (b,bx)
#define PXW_     68                       // u32 pair slots per line
#define LPW_     (C_ * 6 * PXW_)          // wave-private ring (18 lines)
#define NSTRIP_  (B_ * TILES_X_ * SYMAX_) // 16384
#define NBLK_    4096                     // 16 blocks/CU exactly
#define NWAVE_   (NBLK_ * 2)              // 8192 -> 2 strips/wave

typedef __attribute__((ext_vector_type(8)))  short bf16x8;   // MFMA A/B frag
typedef __attribute__((ext_vector_type(16))) float f32x16;   // MFMA C/D frag

// NaN-safe tanh: 1 - 2/(e^{2x}+1); e=inf -> 1 (no inf/inf NaN).
__device__ __forceinline__ float fast_tanh(float v) {
    float e = __expf(2.0f * v);
    return 1.0f - 2.0f * __builtin_amdgcn_rcpf(e + 1.0f);
}
__device__ __forceinline__ uint16_t bf16u(float f) {
    __hip_bfloat16 h = __float2bfloat16(f);   // RNE
    return __builtin_bit_cast(uint16_t, h);
}
__device__ __forceinline__ uint32_t pack2bf(float v0, float v1) {
    return (uint32_t)bf16u(v0) | ((uint32_t)bf16u(v1) << 16);
}
__device__ __forceinline__ float4 ld_f4(const float* p) {
    float4 v;
    __builtin_memcpy(&v, p, 16);   // global_load_dwordx4
    return v;
}

// ---- prep kernel (R19-verified): A-frags (3 ch, permuted rows) + bias ----
// ws: [0) A u16[3][64][8] (3072 B); [3072) bias f32[64][16] (4096 B)
__global__ void conv_prep(const float* __restrict__ wgt,
                          const float* __restrict__ bias,
                          uint16_t* __restrict__ ws16) {
    const int lane = threadIdx.x;        // 0..63
    const int mr = lane & 31;
    const int v  = (mr >> 2) & 1;
    const int oc = (mr & 3) | ((mr >> 3) << 2);
    const int kc = lane >> 5;
    #pragma unroll
    for (int c = 0; c < C_; ++c)
        #pragma unroll
        for (int e = 0; e < 8; ++e) {
            int k  = 8 * kc + e, p = k >> 1, h = k & 1;
            int wr = p >> 1, pk = p & 1;
            int kx = pk ? (h ? -1 : 2) : h;
            int ky = wr - v;
            float w = 0.0f;
            if (kx >= 0 && ky >= 0 && ky <= 2)
                w = wgt[oc * 27 + c * 9 + ky * 3 + kx];
            ws16[(c * 64 + lane) * 8 + e] = bf16u(w);
        }
    float* bp_ = (float*)(ws16 + 1536);  // byte offset 3072
    const int hi = lane >> 5;
    #pragma unroll
    for (int reg = 0; reg < 16; ++reg) {
        int row = (reg & 3) + 8 * (reg >> 2) + 4 * hi;
        bp_[lane * 16 + reg] = bias[(row & 3) | ((row >> 3) << 2)];
    }
}

__global__ __launch_bounds__(128)
void conv3x3_min_tanh_mfma(const float* __restrict__ x,
                           const uint4* __restrict__ wsv,
                           float* __restrict__ out) {
    __shared__ uint32_t lds[2 * LPW_];   // 2 x 4896 B

    const int tid  = threadIdx.x;
    const int lane = tid & 63;
    const int wv   = tid >> 6;
    const int pcol = lane & 31;
    const int hi   = lane >> 5;
    uint32_t* px = lds + wv * LPW_;      // wave-private ring

    // baked A-frags + bias C-init (once per wave, L2-hot 7 KB)
    bf16x8 wfA0 = __builtin_bit_cast(bf16x8, wsv[0 * 64 + lane]);
    bf16x8 wfA1 = __builtin_bit_cast(bf16x8, wsv[1 * 64 + lane]);
    bf16x8 wfA2 = __builtin_bit_cast(bf16x8, wsv[2 * 64 + lane]);
    f32x16 biasv;
    __builtin_memcpy(&biasv, &wsv[192 + lane * 4], 64);

    const int wgid = blockIdx.x * 2 + wv;     // 0..8191
    const int rr_  = lane >> 4;               // staging row 0..3
    const int ch_  = lane & 15;               // staging chunk 0..15

    #pragma unroll 1
    for (int sp = 0; sp < 2; ++sp) {
        const int strip = wgid + sp * NWAVE_;       // 0..16383
        const int b   = strip >> 8;
        const int rem = strip & 255;
        const int bx  = rem & 7;
        const int sy  = rem >> 3;
        const int ox0 = min(bx * 64, OW_ - 64);     // <= 446
        const int oyw = min(16 * sy, OH_ - 16);     // <= 494

        const float* xb = x + (size_t)b * (C_ * H_ * W_);

        // ---- prologue: window rows 0..5 -> slots 0..5 (18 lines) ----
        #pragma unroll 1
        for (int pass = 0; pass < 5; ++pass) {
            int i = pass * 64 + lane;
            if (i < 288) {
                int line = i >> 4;               // c*6 + r
                int x0   = 4 * (i & 15);
                int c    = (line >= 6) + (line >= 12);
                int r    = line - 6 * c;
                const float* xrow = xb + ((size_t)(c * H_) + (oyw + r)) * W_ + ox0;
                float4 v = ld_f4(xrow + x0);
                float v4 = xrow[x0 + 4];
                uint4 pk;
                pk.x = pack2bf(v.x, v.y);
                pk.y = pack2bf(v.y, v.z);
                pk.z = pack2bf(v.z, v.w);
                pk.w = pack2bf(v.w, v4);
                *reinterpret_cast<uint4*>(&px[line * PXW_ + x0]) = pk;
            }
        }
        if (lane < 36) {                         // extras x=64,65 per line
            int line = lane >> 1;
            int xx   = 64 + (lane & 1);
            int c    = (line >= 6) + (line >= 12);
            int r    = line - 6 * c;
            const float* xrow = xb + ((size_t)(c * H_) + (oyw + r)) * W_;
            float v0 = xrow[ox0 + xx];
            float v1 = xrow[min(ox0 + xx + 1, W_ - 1)];
            px[line * PXW_ + xx] = pack2bf(v0, v1);
        }

        const size_t obase0 = ((size_t)b * OH_ + oyw) * OW_ + ox0 + pcol;

        // ---- 4 subtiles, software-pipelined through the 6-slot ring ----
        #pragma unroll 1
        for (int t = 0; t < 4; ++t) {
            // issue next 4 rows' loads (rows 4t+6..4t+9), used after compute
            float4 L0 = {0,0,0,0}, L1 = {0,0,0,0}, L2 = {0,0,0,0};
            float E0 = 0.f, E1 = 0.f, E2 = 0.f, X0 = 0.f, X1 = 0.f;
            if (t < 3) {
                int gy_ = oyw + 4 * t + 6 + rr_;                 // <= 511
                int xo_ = ox0 + 4 * ch_;
                const float* r0_ = xb + (size_t)gy_ * W_ + xo_;
                const float* r1_ = r0_ + (size_t)H_ * W_;
                const float* r2_ = r1_ + (size_t)H_ * W_;
                L0 = ld_f4(r0_); E0 = r0_[4];
                L1 = ld_f4(r1_); E1 = r1_[4];
                L2 = ld_f4(r2_); E2 = r2_[4];
                if (lane < 24) {
                    int le_ = lane >> 1, ce_ = le_ >> 2, re_ = le_ & 3;
                    int xx_ = 64 + (lane & 1);
                    const float* xr_ = xb +
                        ((size_t)(ce_ * H_) + (oyw + 4 * t + 6 + re_)) * W_;
                    X0 = xr_[ox0 + xx_];
                    X1 = xr_[min(ox0 + xx_ + 1, W_ - 1)];
                }
            }

            // 4 groups (gi = row-pair, xh = x-half), rolled; runtime mod-6 slots
            #pragma unroll 1
            for (int g4 = 0; g4 < 4; ++g4) {
                int gi = g4 >> 1, xh = g4 & 1;
                int j  = pcol + 32 * xh;
                int u  = 4 * t + 2 * gi + 2 * hi;   // even, <= 16
                u -= (u >= 6) ? 6 : 0;
                u -= (u >= 6) ? 6 : 0;              // u = slot of first row
                int b00 = u * PXW_ + j;
                int b01 = b00 + PXW_;               // slot u+1 (never wraps: u even <=4)
                int b10 = b00 + 6 * PXW_, b11 = b01 + 6 * PXW_;
                int b20 = b10 + 6 * PXW_, b21 = b11 + 6 * PXW_;
                bf16x8 tb0 = __builtin_bit_cast(bf16x8,
                    uint4{px[b00], px[b00 + 2], px[b01], px[b01 + 2]});
                bf16x8 tb1 = __builtin_bit_cast(bf16x8,
                    uint4{px[b10], px[b10 + 2], px[b11], px[b11 + 2]});
                bf16x8 tb2 = __builtin_bit_cast(bf16x8,
                    uint4{px[b20], px[b20 + 2], px[b21], px[b21 + 2]});
                f32x16 acc = __builtin_amdgcn_mfma_f32_32x32x16_bf16(wfA0, tb0, biasv, 0, 0, 0);
                acc = __builtin_amdgcn_mfma_f32_32x32x16_bf16(wfA1, tb1, acc, 0, 0, 0);
                acc = __builtin_amdgcn_mfma_f32_32x32x16_bf16(wfA2, tb2, acc, 0, 0, 0);
                float n0 = fminf(acc[0], acc[1]),   n1 = fminf(acc[2], acc[3]);
                float n2 = fminf(acc[4], acc[5]),   n3 = fminf(acc[6], acc[7]);
                float n4 = fminf(acc[8], acc[9]),   n5 = fminf(acc[10], acc[11]);
                float n6 = fminf(acc[12], acc[13]), n7 = fminf(acc[14], acc[15]);
                float mm = fminf(fminf(fminf(n0, n1), fminf(n2, n3)),
                                 fminf(fminf(n4, n5), fminf(n6, n7)));
                float t_ = fast_tanh(fast_tanh(mm));
                out[obase0 + (size_t)(4 * t + 2 * gi + hi) * OW_ + 32 * xh] = t_;
            }

            // retire ring slots with the prefetched rows (write-after-read:
            // per-wave DS is in-order; these writes follow this t's reads)
            if (t < 3) {
                int sb_ = 4 * t + 6;
                sb_ -= (sb_ >= 6) ? 6 : 0;
                sb_ -= (sb_ >= 6) ? 6 : 0;          // {0,4,2}
                int s_ = sb_ + rr_;
                s_ -= (s_ >= 6) ? 6 : 0;
                uint4 pk;
                pk.x = pack2bf(L0.x, L0.y); pk.y = pack2bf(L0.y, L0.z);
                pk.z = pack2bf(L0.z, L0.w); pk.w = pack2bf(L0.w, E0);
                *reinterpret_cast<uint4*>(&px[(0 * 6 + s_) * PXW_ + 4 * ch_]) = pk;
                pk.x = pack2bf(L1.x, L1.y); pk.y = pack2bf(L1.y, L1.z);
                pk.z = pack2bf(L1.z, L1.w); pk.w = pack2bf(L1.w, E1);
                *reinterpret_cast<uint4*>(&px[(1 * 6 + s_) * PXW_ + 4 * ch_]) = pk;
                pk.x = pack2bf(L2.x, L2.y); pk.y = pack2bf(L2.y, L2.z);
                pk.z = pack2bf(L2.z, L2.w); pk.w = pack2bf(L2.w, E2);
                *reinterpret_cast<uint4*>(&px[(2 * 6 + s_) * PXW_ + 4 * ch_]) = pk;
                if (lane < 24) {
                    int le_ = lane >> 1, ce_ = le_ >> 2, re_ = le_ & 3;
                    int xx_ = 64 + (lane & 1);
                    int se_ = sb_ + re_;
                    se_ -= (se_ >= 6) ? 6 : 0;
                    px[(ce_ * 6 + se_) * PXW_ + xx_] = pack2bf(X0, X1);
                }
            }
        }
    }
}

extern "C" void kernel_launch(void* const* d_in, const int* in_sizes, int n_in,
                              void* d_out, int out_size, void* d_ws, size_t ws_size,
                              hipStream_t stream) {
    const float* x    = (const float*)d_in[0];
    const float* wgt  = (const float*)d_in[1];
    const float* bias = (const float*)d_in[2];
    float* out = (float*)d_out;

    conv_prep<<<1, 64, 0, stream>>>(wgt, bias, (uint16_t*)d_ws);
    conv3x3_min_tanh_mfma<<<dim3(NBLK_), 128, 0, stream>>>(
        x, (const uint4*)d_ws, out);
}

// Round 22
// 67.255 us; speedup vs baseline: 1.1834x; 1.0861x over previous
//
#include <hip/hip_runtime.h>
#include <hip/hip_bf16.h>
#include <stdint.h>

// Problem constants
#define B_  64
#define C_  3
#define H_  512
#define W_  512
#define OC_ 16
#define OH_ 510
#define OW_ 510

// ROLLED + PERSISTENT + DEEP-STRIP version (evolves R21). Verified math:
//  - 32x32x16 MFMA, M=32 rows = (v,oc) permuted: v=(r>>2)&1, oc=(r&3)|((r>>3)<<2)
//    -> C-layout row=(reg&3)+8*(reg>>2)+4*hi gives pure in-lane channel-min.
//  - wave-private 3ch x 6-row LDS ring (slot = row mod 6).
// New vs R21: strip = 64px x 32 rows (one per wave; halo share halved),
// incremental mod-6 slot base (st += 4 mod 6; retire base == st), group loop
// unroll 2 (two indep read->MFMA->min->tanh chains in flight). No fences.
#define TILES_X_ 8
#define SYMAX_   16                       // 32-row strips per (b,bx)
#define PXW_     68                       // u32 pair slots per line
#define LPW_     (C_ * 6 * PXW_)          // wave-private ring (18 lines)
#define NBLK_    4096                     // 16 blocks/CU, 2 waves/block

typedef __attribute__((ext_vector_type(8)))  short bf16x8;   // MFMA A/B frag
typedef __attribute__((ext_vector_type(16))) float f32x16;   // MFMA C/D frag

// NaN-safe tanh: 1 - 2/(e^{2x}+1); e=inf -> 1 (no inf/inf NaN).
__device__ __forceinline__ float fast_tanh(float v) {
    float e = __expf(2.0f * v);
    return 1.0f - 2.0f * __builtin_amdgcn_rcpf(e + 1.0f);
}
__device__ __forceinline__ uint16_t bf16u(float f) {
    __hip_bfloat16 h = __float2bfloat16(f);   // RNE
    return __builtin_bit_cast(uint16_t, h);
}
__device__ __forceinline__ uint32_t pack2bf(float v0, float v1) {
    return (uint32_t)bf16u(v0) | ((uint32_t)bf16u(v1) << 16);
}
__device__ __forceinline__ float4 ld_f4(const float* p) {
    float4 v;
    __builtin_memcpy(&v, p, 16);   // global_load_dwordx4
    return v;
}

// ---- prep kernel (R19-verified): A-frags (3 ch, permuted rows) + bias ----
// ws: [0) A u16[3][64][8] (3072 B); [3072) bias f32[64][16] (4096 B)
__global__ void conv_prep(const float* __restrict__ wgt,
                          const float* __restrict__ bias,
                          uint16_t* __restrict__ ws16) {
    const int lane = threadIdx.x;        // 0..63
    const int mr = lane & 31;
    const int v  = (mr >> 2) & 1;
    const int oc = (mr & 3) | ((mr >> 3) << 2);
    const int kc = lane >> 5;
    #pragma unroll
    for (int c = 0; c < C_; ++c)
        #pragma unroll
        for (int e = 0; e < 8; ++e) {
            int k  = 8 * kc + e, p = k >> 1, h = k & 1;
            int wr = p >> 1, pk = p & 1;
            int kx = pk ? (h ? -1 : 2) : h;
            int ky = wr - v;
            float w = 0.0f;
            if (kx >= 0 && ky >= 0 && ky <= 2)
                w = wgt[oc * 27 + c * 9 + ky * 3 + kx];
            ws16[(c * 64 + lane) * 8 + e] = bf16u(w);
        }
    float* bp_ = (float*)(ws16 + 1536);  // byte offset 3072
    const int hi = lane >> 5;
    #pragma unroll
    for (int reg = 0; reg < 16; ++reg) {
        int row = (reg & 3) + 8 * (reg >> 2) + 4 * hi;
        bp_[lane * 16 + reg] = bias[(row & 3) | ((row >> 3) << 2)];
    }
}

__global__ __launch_bounds__(128)
void conv3x3_min_tanh_mfma(const float* __restrict__ x,
                           const uint4* __restrict__ wsv,
                           float* __restrict__ out) {
    __shared__ uint32_t lds[2 * LPW_];   // 2 x 4896 B

    const int tid  = threadIdx.x;
    const int lane = tid & 63;
    const int wv   = tid >> 6;
    const int pcol = lane & 31;
    const int hi   = lane >> 5;
    uint32_t* px = lds + wv * LPW_;      // wave-private ring

    // baked A-frags + bias C-init (once per wave, L2-hot 7 KB)
    bf16x8 wfA0 = __builtin_bit_cast(bf16x8, wsv[0 * 64 + lane]);
    bf16x8 wfA1 = __builtin_bit_cast(bf16x8, wsv[1 * 64 + lane]);
    bf16x8 wfA2 = __builtin_bit_cast(bf16x8, wsv[2 * 64 + lane]);
    f32x16 biasv;
    __builtin_memcpy(&biasv, &wsv[192 + lane * 4], 64);

    const int wgid = blockIdx.x * 2 + wv;     // 0..8191 == strip id
    const int rr_  = lane >> 4;               // staging row 0..3
    const int ch_  = lane & 15;               // staging chunk 0..15

    const int b   = wgid >> 7;                // 128 strips per batch image
    const int rem = wgid & 127;
    const int bx  = rem & 7;
    const int sy  = rem >> 3;                 // 0..15
    const int ox0 = min(bx * 64, OW_ - 64);   // <= 446
    const int oyw = min(32 * sy, OH_ - 32);   // <= 478; window rows <= 511

    const float* xb = x + (size_t)b * (C_ * H_ * W_);

    // ---- prologue: wave-local window rows 0..5 -> slots 0..5 (18 lines) ----
    #pragma unroll
    for (int pass = 0; pass < 5; ++pass) {
        int i = pass * 64 + lane;
        if (pass < 4 || lane < 32) {     // 288 items
            int line = i >> 4;           // c*6 + r
            int x0   = 4 * (i & 15);
            int c    = (line >= 6) + (line >= 12);
            int r    = line - 6 * c;
            const float* xrow = xb + ((size_t)(c * H_) + (oyw + r)) * W_ + ox0;
            float4 v = ld_f4(xrow + x0);
            float v4 = xrow[x0 + 4];
            uint4 pk;
            pk.x = pack2bf(v.x, v.y);
            pk.y = pack2bf(v.y, v.z);
            pk.z = pack2bf(v.z, v.w);
            pk.w = pack2bf(v.w, v4);
            *reinterpret_cast<uint4*>(&px[line * PXW_ + x0]) = pk;
        }
    }
    if (lane < 36) {                     // extras x=64,65 per line
        int line = lane >> 1;
        int xx   = 64 + (lane & 1);
        int c    = (line >= 6) + (line >= 12);
        int r    = line - 6 * c;
        const float* xrow = xb + ((size_t)(c * H_) + (oyw + r)) * W_;
        float v0 = xrow[ox0 + xx];
        float v1 = xrow[min(ox0 + xx + 1, W_ - 1)];
        px[line * PXW_ + xx] = pack2bf(v0, v1);
    }

    const size_t obase0 = ((size_t)b * OH_ + oyw) * OW_ + ox0 + pcol;

    // ---- 8 subtiles (4 rows each), pipelined through the 6-slot ring ----
    int st = 0;                          // (4t) mod 6: 0,4,2,0,4,2,0,4
    #pragma unroll 1
    for (int t = 0; t < 8; ++t) {
        // issue next 4 rows' loads (wave-local rows 4t+6..4t+9), write later
        float4 L0 = {0,0,0,0}, L1 = {0,0,0,0}, L2 = {0,0,0,0};
        float E0 = 0.f, E1 = 0.f, E2 = 0.f, X0 = 0.f, X1 = 0.f;
        if (t < 7) {
            int gy_ = oyw + 4 * t + 6 + rr_;                 // <= 511
            int xo_ = ox0 + 4 * ch_;
            const float* r0_ = xb + (size_t)gy_ * W_ + xo_;
            const float* r1_ = r0_ + (size_t)H_ * W_;
            const float* r2_ = r1_ + (size_t)H_ * W_;
            L0 = ld_f4(r0_); E0 = r0_[4];
            L1 = ld_f4(r1_); E1 = r1_[4];
            L2 = ld_f4(r2_); E2 = r2_[4];
            if (lane < 24) {
                int le_ = lane >> 1, ce_ = le_ >> 2, re_ = le_ & 3;
                int xx_ = 64 + (lane & 1);
                const float* xr_ = xb +
                    ((size_t)(ce_ * H_) + (oyw + 4 * t + 6 + re_)) * W_;
                X0 = xr_[ox0 + xx_];
                X1 = xr_[min(ox0 + xx_ + 1, W_ - 1)];
            }
        }

        // 4 groups (gi = row-pair, xh = x-half); unroll 2 -> two independent
        // ds_read->MFMA->min->tanh chains in flight
        #pragma unroll 2
        for (int g4 = 0; g4 < 4; ++g4) {
            int gi = g4 >> 1, xh = g4 & 1;
            int j  = pcol + 32 * xh;
            int u  = st + 2 * gi + 2 * hi;      // even, <= 8
            u -= (u >= 6) ? 6 : 0;              // slot of first row (even, <=4)
            int b00 = u * PXW_ + j;
            int b01 = b00 + PXW_;               // slot u+1 (never wraps)
            int b10 = b00 + 6 * PXW_, b11 = b01 + 6 * PXW_;
            int b20 = b10 + 6 * PXW_, b21 = b11 + 6 * PXW_;
            bf16x8 tb0 = __builtin_bit_cast(bf16x8,
                uint4{px[b00], px[b00 + 2], px[b01], px[b01 + 2]});
            bf16x8 tb1 = __builtin_bit_cast(bf16x8,
                uint4{px[b10], px[b10 + 2], px[b11], px[b11 + 2]});
            bf16x8 tb2 = __builtin_bit_cast(bf16x8,
                uint4{px[b20], px[b20 + 2], px[b21], px[b21 + 2]});
            f32x16 acc = __builtin_amdgcn_mfma_f32_32x32x16_bf16(wfA0, tb0, biasv, 0, 0, 0);
            acc = __builtin_amdgcn_mfma_f32_32x32x16_bf16(wfA1, tb1, acc, 0, 0, 0);
            acc = __builtin_amdgcn_mfma_f32_32x32x16_bf16(wfA2, tb2, acc, 0, 0, 0);
            float n0 = fminf(acc[0], acc[1]),   n1 = fminf(acc[2], acc[3]);
            float n2 = fminf(acc[4], acc[5]),   n3 = fminf(acc[6], acc[7]);
            float n4 = fminf(acc[8], acc[9]),   n5 = fminf(acc[10], acc[11]);
            float n6 = fminf(acc[12], acc[13]), n7 = fminf(acc[14], acc[15]);
            float mm = fminf(fminf(fminf(n0, n1), fminf(n2, n3)),
                             fminf(fminf(n4, n5), fminf(n6, n7)));
            float t_ = fast_tanh(fast_tanh(mm));
            out[obase0 + (size_t)(4 * t + 2 * gi + hi) * OW_ + 32 * xh] = t_;
        }

        // retire ring slots with prefetched rows. Slot of row 4t+6 is
        // (4t+6)%6 == (4t)%6 == st. Per-wave DS is in-order: these writes
        // follow this t's reads.
        if (t < 7) {
            int s_ = st + rr_;                  // <= 7
            s_ -= (s_ >= 6) ? 6 : 0;
            uint4 pk;
            pk.x = pack2bf(L0.x, L0.y); pk.y = pack2bf(L0.y, L0.z);
            pk.z = pack2bf(L0.z, L0.w); pk.w = pack2bf(L0.w, E0);
            *reinterpret_cast<uint4*>(&px[(0 * 6 + s_) * PXW_ + 4 * ch_]) = pk;
            pk.x = pack2bf(L1.x, L1.y); pk.y = pack2bf(L1.y, L1.z);
            pk.z = pack2bf(L1.z, L1.w); pk.w = pack2bf(L1.w, E1);
            *reinterpret_cast<uint4*>(&px[(1 * 6 + s_) * PXW_ + 4 * ch_]) = pk;
            pk.x = pack2bf(L2.x, L2.y); pk.y = pack2bf(L2.y, L2.z);
            pk.z = pack2bf(L2.z, L2.w); pk.w = pack2bf(L2.w, E2);
            *reinterpret_cast<uint4*>(&px[(2 * 6 + s_) * PXW_ + 4 * ch_]) = pk;
            if (lane < 24) {
                int le_ = lane >> 1, ce_ = le_ >> 2, re_ = le_ & 3;
                int xx_ = 64 + (lane & 1);
                int se_ = st + re_;
                se_ -= (se_ >= 6) ? 6 : 0;
                px[(ce_ * 6 + se_) * PXW_ + xx_] = pack2bf(X0, X1);
            }
        }

        st += 4;
        st -= (st >= 6) ? 6 : 0;
    }
}

extern "C" void kernel_launch(void* const* d_in, const int* in_sizes, int n_in,
                              void* d_out, int out_size, void* d_ws, size_t ws_size,
                              hipStream_t stream) {
    const float* x    = (const float*)d_in[0];
    const float* wgt  = (const float*)d_in[1];
    const float* bias = (const float*)d_in[2];
    float* out = (float*)d_out;

    conv_prep<<<1, 64, 0, stream>>>(wgt, bias, (uint16_t*)d_ws);
    conv3x3_min_tanh_mfma<<<dim3(NBLK_), 128, 0, stream>>>(
        x, (const uint4*)d_ws, out);
}

// Round 23
// 66.503 us; speedup vs baseline: 1.1968x; 1.0113x over previous
//
#include <hip/hip_runtime.h>
#include <hip/hip_bf16.h>
#include <stdint.h>

// Problem constants
#define B_  64
#define C_  3
#define H_  512
#define W_  512
#define OC_ 16
#define OH_ 510
#define OW_ 510

// ROLLED + PERSISTENT + DEEP-STRIP (R22) + MORE ILP (this round):
//  - group loop fully unrolled (4 indep read->MFMA->min->tanh chains),
//  - t-loop unroll 2 (loads of t+1 interleave with compute/retire of t),
//  - hoisted staging pointers.
// Verified math unchanged: 32x32x16 MFMA, M-rows (v,oc)-permuted
// (v=(r>>2)&1, oc=(r&3)|((r>>3)<<2)) -> pure in-lane channel-min;
// wave-private 3ch x 6-row LDS ring (slot = row mod 6); 64px x 32row strip.
#define TILES_X_ 8
#define PXW_     68                       // u32 pair slots per line
#define LPW_     (C_ * 6 * PXW_)          // wave-private ring (18 lines)
#define NBLK_    4096                     // 16 blocks/CU, 2 waves/block

typedef __attribute__((ext_vector_type(8)))  short bf16x8;   // MFMA A/B frag
typedef __attribute__((ext_vector_type(16))) float f32x16;   // MFMA C/D frag

// NaN-safe tanh: 1 - 2/(e^{2x}+1); e=inf -> 1 (no inf/inf NaN).
__device__ __forceinline__ float fast_tanh(float v) {
    float e = __expf(2.0f * v);
    return 1.0f - 2.0f * __builtin_amdgcn_rcpf(e + 1.0f);
}
__device__ __forceinline__ uint16_t bf16u(float f) {
    __hip_bfloat16 h = __float2bfloat16(f);   // RNE
    return __builtin_bit_cast(uint16_t, h);
}
__device__ __forceinline__ uint32_t pack2bf(float v0, float v1) {
    return (uint32_t)bf16u(v0) | ((uint32_t)bf16u(v1) << 16);
}
__device__ __forceinline__ float4 ld_f4(const float* p) {
    float4 v;
    __builtin_memcpy(&v, p, 16);   // global_load_dwordx4
    return v;
}

// ---- prep kernel (R19-verified): A-frags (3 ch, permuted rows) + bias ----
// ws: [0) A u16[3][64][8] (3072 B); [3072) bias f32[64][16] (4096 B)
__global__ void conv_prep(const float* __restrict__ wgt,
                          const float* __restrict__ bias,
                          uint16_t* __restrict__ ws16) {
    const int lane = threadIdx.x;        // 0..63
    const int mr = lane & 31;
    const int v  = (mr >> 2) & 1;
    const int oc = (mr & 3) | ((mr >> 3) << 2);
    const int kc = lane >> 5;
    #pragma unroll
    for (int c = 0; c < C_; ++c)
        #pragma unroll
        for (int e = 0; e < 8; ++e) {
            int k  = 8 * kc + e, p = k >> 1, h = k & 1;
            int wr = p >> 1, pk = p & 1;
            int kx = pk ? (h ? -1 : 2) : h;
            int ky = wr - v;
            float w = 0.0f;
            if (kx >= 0 && ky >= 0 && ky <= 2)
                w = wgt[oc * 27 + c * 9 + ky * 3 + kx];
            ws16[(c * 64 + lane) * 8 + e] = bf16u(w);
        }
    float* bp_ = (float*)(ws16 + 1536);  // byte offset 3072
    const int hi = lane >> 5;
    #pragma unroll
    for (int reg = 0; reg < 16; ++reg) {
        int row = (reg & 3) + 8 * (reg >> 2) + 4 * hi;
        bp_[lane * 16 + reg] = bias[(row & 3) | ((row >> 3) << 2)];
    }
}

__global__ __launch_bounds__(128)
void conv3x3_min_tanh_mfma(const float* __restrict__ x,
                           const uint4* __restrict__ wsv,
                           float* __restrict__ out) {
    __shared__ uint32_t lds[2 * LPW_];   // 2 x 4896 B

    const int tid  = threadIdx.x;
    const int lane = tid & 63;
    const int wv   = tid >> 6;
    const int pcol = lane & 31;
    const int hi   = lane >> 5;
    uint32_t* px = lds + wv * LPW_;      // wave-private ring

    // baked A-frags + bias C-init (once per wave, L2-hot 7 KB)
    bf16x8 wfA0 = __builtin_bit_cast(bf16x8, wsv[0 * 64 + lane]);
    bf16x8 wfA1 = __builtin_bit_cast(bf16x8, wsv[1 * 64 + lane]);
    bf16x8 wfA2 = __builtin_bit_cast(bf16x8, wsv[2 * 64 + lane]);
    f32x16 biasv;
    __builtin_memcpy(&biasv, &wsv[192 + lane * 4], 64);

    const int wgid = blockIdx.x * 2 + wv;     // 0..8191 == strip id
    const int rr_  = lane >> 4;               // staging row 0..3
    const int ch_  = lane & 15;               // staging chunk 0..15

    const int b   = wgid >> 7;                // 128 strips per batch image
    const int rem = wgid & 127;
    const int bx  = rem & 7;
    const int sy  = rem >> 3;                 // 0..15
    const int ox0 = min(bx * 64, OW_ - 64);   // <= 446
    const int oyw = min(32 * sy, OH_ - 32);   // <= 478; window rows <= 511

    const float* xb = x + (size_t)b * (C_ * H_ * W_);

    // ---- prologue: wave-local window rows 0..5 -> slots 0..5 (18 lines) ----
    #pragma unroll
    for (int pass = 0; pass < 5; ++pass) {
        int i = pass * 64 + lane;
        if (pass < 4 || lane < 32) {     // 288 items
            int line = i >> 4;           // c*6 + r
            int x0   = 4 * (i & 15);
            int c    = (line >= 6) + (line >= 12);
            int r    = line - 6 * c;
            const float* xrow = xb + ((size_t)(c * H_) + (oyw + r)) * W_ + ox0;
            float4 v = ld_f4(xrow + x0);
            float v4 = xrow[x0 + 4];
            uint4 pk;
            pk.x = pack2bf(v.x, v.y);
            pk.y = pack2bf(v.y, v.z);
            pk.z = pack2bf(v.z, v.w);
            pk.w = pack2bf(v.w, v4);
            *reinterpret_cast<uint4*>(&px[line * PXW_ + x0]) = pk;
        }
    }
    if (lane < 36) {                     // extras x=64,65 per line
        int line = lane >> 1;
        int xx   = 64 + (lane & 1);
        int c    = (line >= 6) + (line >= 12);
        int r    = line - 6 * c;
        const float* xrow = xb + ((size_t)(c * H_) + (oyw + r)) * W_;
        float v0 = xrow[ox0 + xx];
        float v1 = xrow[min(ox0 + xx + 1, W_ - 1)];
        px[line * PXW_ + xx] = pack2bf(v0, v1);
    }

    const size_t obase0 = ((size_t)b * OH_ + oyw) * OW_ + ox0 + pcol;

    // hoisted staging pointers: row (oyw + 6 + rr_), advanced 4*W_ per t
    const float* pr0 = xb + ((size_t)(oyw + 6 + rr_)) * W_ + ox0 + 4 * ch_;
    const float* pr1 = pr0 + (size_t)H_ * W_;
    const float* pr2 = pr1 + (size_t)H_ * W_;
    // extras pointer (lanes 0..23): channel ce_, row offset re_
    const int le_ = lane >> 1, ce_ = le_ >> 2, re_ = le_ & 3;
    const int xxe = 64 + (lane & 1);
    const float* pre = xb + ((size_t)(ce_ * H_) + (oyw + 6 + re_)) * W_;
    const int exa = ox0 + xxe;
    const int exb = min(ox0 + xxe + 1, W_ - 1);

    // one group: compile-time gi/xh, runtime slot base u (even, <=4)
#define GROUP(gi, xh, u)                                                       \
    {                                                                          \
        const int j   = pcol + 32 * (xh);                                      \
        const int b00 = (u) * PXW_ + j;                                        \
        const int b01 = b00 + PXW_;                                            \
        const int b10 = b00 + 6 * PXW_, b11 = b01 + 6 * PXW_;                  \
        const int b20 = b10 + 6 * PXW_, b21 = b11 + 6 * PXW_;                  \
        bf16x8 tb0 = __builtin_bit_cast(bf16x8,                                \
            uint4{px[b00], px[b00 + 2], px[b01], px[b01 + 2]});                \
        bf16x8 tb1 = __builtin_bit_cast(bf16x8,                                \
            uint4{px[b10], px[b10 + 2], px[b11], px[b11 + 2]});                \
        bf16x8 tb2 = __builtin_bit_cast(bf16x8,                                \
            uint4{px[b20], px[b20 + 2], px[b21], px[b21 + 2]});                \
        f32x16 acc = __builtin_amdgcn_mfma_f32_32x32x16_bf16(wfA0, tb0, biasv, 0, 0, 0); \
        acc = __builtin_amdgcn_mfma_f32_32x32x16_bf16(wfA1, tb1, acc, 0, 0, 0);\
        acc = __builtin_amdgcn_mfma_f32_32x32x16_bf16(wfA2, tb2, acc, 0, 0, 0);\
        float n0 = fminf(acc[0], acc[1]),   n1 = fminf(acc[2], acc[3]);        \
        float n2 = fminf(acc[4], acc[5]),   n3 = fminf(acc[6], acc[7]);        \
        float n4 = fminf(acc[8], acc[9]),   n5 = fminf(acc[10], acc[11]);      \
        float n6 = fminf(acc[12], acc[13]), n7 = fminf(acc[14], acc[15]);      \
        float mm = fminf(fminf(fminf(n0, n1), fminf(n2, n3)),                  \
                         fminf(fminf(n4, n5), fminf(n6, n7)));                 \
        float t_ = fast_tanh(fast_tanh(mm));                                   \
        out[obase0 + (size_t)(4 * t + 2 * (gi) + hi) * OW_ + 32 * (xh)] = t_;  \
    }

    // ---- 8 subtiles (4 rows each) through the 6-slot ring; unroll 2 ----
    int st = 0;                          // (4t) mod 6: 0,4,2,...
    #pragma unroll 2
    for (int t = 0; t < 8; ++t) {
        // issue next 4 rows' loads (wave-local rows 4t+6..4t+9)
        float4 L0 = {0,0,0,0}, L1 = {0,0,0,0}, L2 = {0,0,0,0};
        float E0 = 0.f, E1 = 0.f, E2 = 0.f, X0 = 0.f, X1 = 0.f;
        if (t < 7) {
            const float* r0_ = pr0 + (size_t)(4 * t) * W_;
            const float* r1_ = pr1 + (size_t)(4 * t) * W_;
            const float* r2_ = pr2 + (size_t)(4 * t) * W_;
            L0 = ld_f4(r0_); E0 = r0_[4];
            L1 = ld_f4(r1_); E1 = r1_[4];
            L2 = ld_f4(r2_); E2 = r2_[4];
            if (lane < 24) {
                const float* xr_ = pre + (size_t)(4 * t) * W_;
                X0 = xr_[exa];
                X1 = xr_[exb];
            }
        }

        // 4 groups fully unrolled; slot bases from loop-carried st
        {
            int u0 = st + 2 * hi;  u0 -= (u0 >= 6) ? 6 : 0;   // gi=0
            int u1 = u0 + 2;       u1 -= (u1 >= 6) ? 6 : 0;   // gi=1
            GROUP(0, 0, u0)
            GROUP(0, 1, u0)
            GROUP(1, 0, u1)
            GROUP(1, 1, u1)
        }

        // retire ring slots with prefetched rows (slot of row 4t+6 == st);
        // per-wave DS is in-order: these writes follow this t's reads.
        if (t < 7) {
            int s_ = st + rr_;
            s_ -= (s_ >= 6) ? 6 : 0;
            uint4 pk;
            pk.x = pack2bf(L0.x, L0.y); pk.y = pack2bf(L0.y, L0.z);
            pk.z = pack2bf(L0.z, L0.w); pk.w = pack2bf(L0.w, E0);
            *reinterpret_cast<uint4*>(&px[(0 * 6 + s_) * PXW_ + 4 * ch_]) = pk;
            pk.x = pack2bf(L1.x, L1.y); pk.y = pack2bf(L1.y, L1.z);
            pk.z = pack2bf(L1.z, L1.w); pk.w = pack2bf(L1.w, E1);
            *reinterpret_cast<uint4*>(&px[(1 * 6 + s_) * PXW_ + 4 * ch_]) = pk;
            pk.x = pack2bf(L2.x, L2.y); pk.y = pack2bf(L2.y, L2.z);
            pk.z = pack2bf(L2.z, L2.w); pk.w = pack2bf(L2.w, E2);
            *reinterpret_cast<uint4*>(&px[(2 * 6 + s_) * PXW_ + 4 * ch_]) = pk;
            if (lane < 24) {
                int se_ = st + re_;
                se_ -= (se_ >= 6) ? 6 : 0;
                px[(ce_ * 6 + se_) * PXW_ + xxe] = pack2bf(X0, X1);
            }
        }

        st += 4;
        st -= (st >= 6) ? 6 : 0;
    }
#undef GROUP
}

extern "C" void kernel_launch(void* const* d_in, const int* in_sizes, int n_in,
                              void* d_out, int out_size, void* d_ws, size_t ws_size,
                              hipStream_t stream) {
    const float* x    = (const float*)d_in[0];
    const float* wgt  = (const float*)d_in[1];
    const float* bias = (const float*)d_in[2];
    float* out = (float*)d_out;

    conv_prep<<<1, 64, 0, stream>>>(wgt, bias, (uint16_t*)d_ws);
    conv3x3_min_tanh_mfma<<<dim3(NBLK_), 128, 0, stream>>>(
        x, (const uint4*)d_ws, out);
}

// Round 24
// 65.142 us; speedup vs baseline: 1.2218x; 1.0209x over previous
//
#include <hip/hip_runtime.h>
#include <hip/hip_bf16.h>
#include <stdint.h>

// Problem constants
#define B_  64
#define C_  3
#define H_  512
#define W_  512
#define OC_ 16
#define OH_ 510
#define OW_ 510

// R23 + __launch_bounds__(128, 4): force VGPR<=128 -> 4 waves/SIMD.
// Single-variable occupancy experiment (code otherwise identical to R23).
// Verified math unchanged: 32x32x16 MFMA, M-rows (v,oc)-permuted
// (v=(r>>2)&1, oc=(r&3)|((r>>3)<<2)) -> pure in-lane channel-min;
// wave-private 3ch x 6-row LDS ring (slot = row mod 6); 64px x 32row strip.
#define TILES_X_ 8
#define PXW_     68                       // u32 pair slots per line
#define LPW_     (C_ * 6 * PXW_)          // wave-private ring (18 lines)
#define NBLK_    4096                     // 16 blocks/CU, 2 waves/block

typedef __attribute__((ext_vector_type(8)))  short bf16x8;   // MFMA A/B frag
typedef __attribute__((ext_vector_type(16))) float f32x16;   // MFMA C/D frag

// NaN-safe tanh: 1 - 2/(e^{2x}+1); e=inf -> 1 (no inf/inf NaN).
__device__ __forceinline__ float fast_tanh(float v) {
    float e = __expf(2.0f * v);
    return 1.0f - 2.0f * __builtin_amdgcn_rcpf(e + 1.0f);
}
__device__ __forceinline__ uint16_t bf16u(float f) {
    __hip_bfloat16 h = __float2bfloat16(f);   // RNE
    return __builtin_bit_cast(uint16_t, h);
}
__device__ __forceinline__ uint32_t pack2bf(float v0, float v1) {
    return (uint32_t)bf16u(v0) | ((uint32_t)bf16u(v1) << 16);
}
__device__ __forceinline__ float4 ld_f4(const float* p) {
    float4 v;
    __builtin_memcpy(&v, p, 16);   // global_load_dwordx4
    return v;
}

// ---- prep kernel (R19-verified): A-frags (3 ch, permuted rows) + bias ----
// ws: [0) A u16[3][64][8] (3072 B); [3072) bias f32[64][16] (4096 B)
__global__ void conv_prep(const float* __restrict__ wgt,
                          const float* __restrict__ bias,
                          uint16_t* __restrict__ ws16) {
    const int lane = threadIdx.x;        // 0..63
    const int mr = lane & 31;
    const int v  = (mr >> 2) & 1;
    const int oc = (mr & 3) | ((mr >> 3) << 2);
    const int kc = lane >> 5;
    #pragma unroll
    for (int c = 0; c < C_; ++c)
        #pragma unroll
        for (int e = 0; e < 8; ++e) {
            int k  = 8 * kc + e, p = k >> 1, h = k & 1;
            int wr = p >> 1, pk = p & 1;
            int kx = pk ? (h ? -1 : 2) : h;
            int ky = wr - v;
            float w = 0.0f;
            if (kx >= 0 && ky >= 0 && ky <= 2)
                w = wgt[oc * 27 + c * 9 + ky * 3 + kx];
            ws16[(c * 64 + lane) * 8 + e] = bf16u(w);
        }
    float* bp_ = (float*)(ws16 + 1536);  // byte offset 3072
    const int hi = lane >> 5;
    #pragma unroll
    for (int reg = 0; reg < 16; ++reg) {
        int row = (reg & 3) + 8 * (reg >> 2) + 4 * hi;
        bp_[lane * 16 + reg] = bias[(row & 3) | ((row >> 3) << 2)];
    }
}

__global__ __launch_bounds__(128, 4)
void conv3x3_min_tanh_mfma(const float* __restrict__ x,
                           const uint4* __restrict__ wsv,
                           float* __restrict__ out) {
    __shared__ uint32_t lds[2 * LPW_];   // 2 x 4896 B

    const int tid  = threadIdx.x;
    const int lane = tid & 63;
    const int wv   = tid >> 6;
    const int pcol = lane & 31;
    const int hi   = lane >> 5;
    uint32_t* px = lds + wv * LPW_;      // wave-private ring

    // baked A-frags + bias C-init (once per wave, L2-hot 7 KB)
    bf16x8 wfA0 = __builtin_bit_cast(bf16x8, wsv[0 * 64 + lane]);
    bf16x8 wfA1 = __builtin_bit_cast(bf16x8, wsv[1 * 64 + lane]);
    bf16x8 wfA2 = __builtin_bit_cast(bf16x8, wsv[2 * 64 + lane]);
    f32x16 biasv;
    __builtin_memcpy(&biasv, &wsv[192 + lane * 4], 64);

    const int wgid = blockIdx.x * 2 + wv;     // 0..8191 == strip id
    const int rr_  = lane >> 4;               // staging row 0..3
    const int ch_  = lane & 15;               // staging chunk 0..15

    const int b   = wgid >> 7;                // 128 strips per batch image
    const int rem = wgid & 127;
    const int bx  = rem & 7;
    const int sy  = rem >> 3;                 // 0..15
    const int ox0 = min(bx * 64, OW_ - 64);   // <= 446
    const int oyw = min(32 * sy, OH_ - 32);   // <= 478; window rows <= 511

    const float* xb = x + (size_t)b * (C_ * H_ * W_);

    // ---- prologue: wave-local window rows 0..5 -> slots 0..5 (18 lines) ----
    #pragma unroll
    for (int pass = 0; pass < 5; ++pass) {
        int i = pass * 64 + lane;
        if (pass < 4 || lane < 32) {     // 288 items
            int line = i >> 4;           // c*6 + r
            int x0   = 4 * (i & 15);
            int c    = (line >= 6) + (line >= 12);
            int r    = line - 6 * c;
            const float* xrow = xb + ((size_t)(c * H_) + (oyw + r)) * W_ + ox0;
            float4 v = ld_f4(xrow + x0);
            float v4 = xrow[x0 + 4];
            uint4 pk;
            pk.x = pack2bf(v.x, v.y);
            pk.y = pack2bf(v.y, v.z);
            pk.z = pack2bf(v.z, v.w);
            pk.w = pack2bf(v.w, v4);
            *reinterpret_cast<uint4*>(&px[line * PXW_ + x0]) = pk;
        }
    }
    if (lane < 36) {                     // extras x=64,65 per line
        int line = lane >> 1;
        int xx   = 64 + (lane & 1);
        int c    = (line >= 6) + (line >= 12);
        int r    = line - 6 * c;
        const float* xrow = xb + ((size_t)(c * H_) + (oyw + r)) * W_;
        float v0 = xrow[ox0 + xx];
        float v1 = xrow[min(ox0 + xx + 1, W_ - 1)];
        px[line * PXW_ + xx] = pack2bf(v0, v1);
    }

    const size_t obase0 = ((size_t)b * OH_ + oyw) * OW_ + ox0 + pcol;

    // hoisted staging pointers: row (oyw + 6 + rr_), advanced 4*W_ per t
    const float* pr0 = xb + ((size_t)(oyw + 6 + rr_)) * W_ + ox0 + 4 * ch_;
    const float* pr1 = pr0 + (size_t)H_ * W_;
    const float* pr2 = pr1 + (size_t)H_ * W_;
    // extras pointer (lanes 0..23): channel ce_, row offset re_
    const int le_ = lane >> 1, ce_ = le_ >> 2, re_ = le_ & 3;
    const int xxe = 64 + (lane & 1);
    const float* pre = xb + ((size_t)(ce_ * H_) + (oyw + 6 + re_)) * W_;
    const int exa = ox0 + xxe;
    const int exb = min(ox0 + xxe + 1, W_ - 1);

    // one group: compile-time gi/xh, runtime slot base u (even, <=4)
#define GROUP(gi, xh, u)                                                       \
    {                                                                          \
        const int j   = pcol + 32 * (xh);                                      \
        const int b00 = (u) * PXW_ + j;                                        \
        const int b01 = b00 + PXW_;                                            \
        const int b10 = b00 + 6 * PXW_, b11 = b01 + 6 * PXW_;                  \
        const int b20 = b10 + 6 * PXW_, b21 = b11 + 6 * PXW_;                  \
        bf16x8 tb0 = __builtin_bit_cast(bf16x8,                                \
            uint4{px[b00], px[b00 + 2], px[b01], px[b01 + 2]});                \
        bf16x8 tb1 = __builtin_bit_cast(bf16x8,                                \
            uint4{px[b10], px[b10 + 2], px[b11], px[b11 + 2]});                \
        bf16x8 tb2 = __builtin_bit_cast(bf16x8,                                \
            uint4{px[b20], px[b20 + 2], px[b21], px[b21 + 2]});                \
        f32x16 acc = __builtin_amdgcn_mfma_f32_32x32x16_bf16(wfA0, tb0, biasv, 0, 0, 0); \
        acc = __builtin_amdgcn_mfma_f32_32x32x16_bf16(wfA1, tb1, acc, 0, 0, 0);\
        acc = __builtin_amdgcn_mfma_f32_32x32x16_bf16(wfA2, tb2, acc, 0, 0, 0);\
        float n0 = fminf(acc[0], acc[1]),   n1 = fminf(acc[2], acc[3]);        \
        float n2 = fminf(acc[4], acc[5]),   n3 = fminf(acc[6], acc[7]);        \
        float n4 = fminf(acc[8], acc[9]),   n5 = fminf(acc[10], acc[11]);      \
        float n6 = fminf(acc[12], acc[13]), n7 = fminf(acc[14], acc[15]);      \
        float mm = fminf(fminf(fminf(n0, n1), fminf(n2, n3)),                  \
                         fminf(fminf(n4, n5), fminf(n6, n7)));                 \
        float t_ = fast_tanh(fast_tanh(mm));                                   \
        out[obase0 + (size_t)(4 * t + 2 * (gi) + hi) * OW_ + 32 * (xh)] = t_;  \
    }

    // ---- 8 subtiles (4 rows each) through the 6-slot ring; unroll 2 ----
    int st = 0;                          // (4t) mod 6: 0,4,2,...
    #pragma unroll 2
    for (int t = 0; t < 8; ++t) {
        // issue next 4 rows' loads (wave-local rows 4t+6..4t+9)
        float4 L0 = {0,0,0,0}, L1 = {0,0,0,0}, L2 = {0,0,0,0};
        float E0 = 0.f, E1 = 0.f, E2 = 0.f, X0 = 0.f, X1 = 0.f;
        if (t < 7) {
            const float* r0_ = pr0 + (size_t)(4 * t) * W_;
            const float* r1_ = pr1 + (size_t)(4 * t) * W_;
            const float* r2_ = pr2 + (size_t)(4 * t) * W_;
            L0 = ld_f4(r0_); E0 = r0_[4];
            L1 = ld_f4(r1_); E1 = r1_[4];
            L2 = ld_f4(r2_); E2 = r2_[4];
            if (lane < 24) {
                const float* xr_ = pre + (size_t)(4 * t) * W_;
                X0 = xr_[exa];
                X1 = xr_[exb];
            }
        }

        // 4 groups fully unrolled; slot bases from loop-carried st
        {
            int u0 = st + 2 * hi;  u0 -= (u0 >= 6) ? 6 : 0;   // gi=0
            int u1 = u0 + 2;       u1 -= (u1 >= 6) ? 6 : 0;   // gi=1
            GROUP(0, 0, u0)
            GROUP(0, 1, u0)
            GROUP(1, 0, u1)
            GROUP(1, 1, u1)
        }

        // retire ring slots with prefetched rows (slot of row 4t+6 == st);
        // per-wave DS is in-order: these writes follow this t's reads.
        if (t < 7) {
            int s_ = st + rr_;
            s_ -= (s_ >= 6) ? 6 : 0;
            uint4 pk;
            pk.x = pack2bf(L0.x, L0.y); pk.y = pack2bf(L0.y, L0.z);
            pk.z = pack2bf(L0.z, L0.w); pk.w = pack2bf(L0.w, E0);
            *reinterpret_cast<uint4*>(&px[(0 * 6 + s_) * PXW_ + 4 * ch_]) = pk;
            pk.x = pack2bf(L1.x, L1.y); pk.y = pack2bf(L1.y, L1.z);
            pk.z = pack2bf(L1.z, L1.w); pk.w = pack2bf(L1.w, E1);
            *reinterpret_cast<uint4*>(&px[(1 * 6 + s_) * PXW_ + 4 * ch_]) = pk;
            pk.x = pack2bf(L2.x, L2.y); pk.y = pack2bf(L2.y, L2.z);
            pk.z = pack2bf(L2.z, L2.w); pk.w = pack2bf(L2.w, E2);
            *reinterpret_cast<uint4*>(&px[(2 * 6 + s_) * PXW_ + 4 * ch_]) = pk;
            if (lane < 24) {
                int se_ = st + re_;
                se_ -= (se_ >= 6) ? 6 : 0;
                px[(ce_ * 6 + se_) * PXW_ + xxe] = pack2bf(X0, X1);
            }
        }

        st += 4;
        st -= (st >= 6) ? 6 : 0;
    }
#undef GROUP
}

extern "C" void kernel_launch(void* const* d_in, const int* in_sizes, int n_in,
                              void* d_out, int out_size, void* d_ws, size_t ws_size,
                              hipStream_t stream) {
    const float* x    = (const float*)d_in[0];
    const float* wgt  = (const float*)d_in[1];
    const float* bias = (const float*)d_in[2];
    float* out = (float*)d_out;

    conv_prep<<<1, 64, 0, stream>>>(wgt, bias, (uint16_t*)d_ws);
    conv3x3_min_tanh_mfma<<<dim3(NBLK_), 128, 0, stream>>>(
        x, (const uint4*)d_ws, out);
}